// Round 1
// baseline (209.694 us; speedup 1.0000x reference)
//
#include <hip/hip_runtime.h>

#define N_NODES 100000
#define N_EDGES 1600000
#define IN_DIM 128
#define OUT_DIM 64

// ---------------------------------------------------------------------------
// Kernel 1: X_prime = X @ W   (f32 vector ALU; no fp32 MFMA on CDNA4)
// Block = 256 threads = 4 waves. W kept transposed in LDS (stride 132 floats
// keeps float4 16B-aligned; b128 reads land at the inherent 8-slot bank floor).
// Each wave: lane = output column, 4 rows of register accumulators.
// ---------------------------------------------------------------------------
__global__ __launch_bounds__(256) void gemm_xw(const float* __restrict__ X,
                                               const float* __restrict__ W,
                                               float* __restrict__ XP,
                                               int nRows) {
    __shared__ float Wt[64][132];   // Wt[c][k], padded stride
    __shared__ float Xt[16][132];   // 16-row X tile, padded stride

    const int t = threadIdx.x;
    // Stage + transpose W (one time per block)
    for (int idx = t; idx < IN_DIM * OUT_DIM; idx += 256) {
        int k = idx >> 6;       // row of W (k index)
        int c = idx & 63;       // col of W
        Wt[c][k] = W[idx];
    }
    __syncthreads();

    const int lane = t & 63;
    const int wid  = t >> 6;
    const int nTiles = (nRows + 15) >> 4;

    for (int tile = blockIdx.x; tile < nTiles; tile += gridDim.x) {
        const int rowBase = tile << 4;
        // Cooperative load of 16 rows x 128 floats = 512 float4 (coalesced)
        for (int f = t; f < 512; f += 256) {
            int r  = f >> 5;       // 32 float4 per row
            int kq = f & 31;
            int gr = rowBase + r;
            float4 v = make_float4(0.f, 0.f, 0.f, 0.f);
            if (gr < nRows) v = *(const float4*)&X[(size_t)gr * IN_DIM + kq * 4];
            *(float4*)&Xt[r][kq * 4] = v;
        }
        __syncthreads();

        const int r0 = wid * 4;
        float acc0 = 0.f, acc1 = 0.f, acc2 = 0.f, acc3 = 0.f;
        #pragma unroll
        for (int kq = 0; kq < 32; ++kq) {
            float4 wv = *(const float4*)&Wt[lane][kq * 4];     // per-lane b128
            float4 x0 = *(const float4*)&Xt[r0 + 0][kq * 4];   // wave-uniform (broadcast)
            float4 x1 = *(const float4*)&Xt[r0 + 1][kq * 4];
            float4 x2 = *(const float4*)&Xt[r0 + 2][kq * 4];
            float4 x3 = *(const float4*)&Xt[r0 + 3][kq * 4];
            acc0 += x0.x * wv.x + x0.y * wv.y + x0.z * wv.z + x0.w * wv.w;
            acc1 += x1.x * wv.x + x1.y * wv.y + x1.z * wv.z + x1.w * wv.w;
            acc2 += x2.x * wv.x + x2.y * wv.y + x2.z * wv.z + x2.w * wv.w;
            acc3 += x3.x * wv.x + x3.y * wv.y + x3.z * wv.z + x3.w * wv.w;
        }
        // Store: per row, 64 lanes write 256B contiguous
        int gr = rowBase + r0;
        if (gr + 0 < nRows) XP[(size_t)(gr + 0) * OUT_DIM + lane] = acc0;
        if (gr + 1 < nRows) XP[(size_t)(gr + 1) * OUT_DIM + lane] = acc1;
        if (gr + 2 < nRows) XP[(size_t)(gr + 2) * OUT_DIM + lane] = acc2;
        if (gr + 3 < nRows) XP[(size_t)(gr + 3) * OUT_DIM + lane] = acc3;
        __syncthreads();
    }
}

// ---------------------------------------------------------------------------
// Kernel 2: row_ptr[i] = lower_bound(edge_src, i) for i in [0, N]
// edge_src is sorted, so mark boundaries; total fill work = N + E.
// ---------------------------------------------------------------------------
__global__ __launch_bounds__(256) void build_row_ptr(const int* __restrict__ src,
                                                     int* __restrict__ row_ptr) {
    int e = blockIdx.x * blockDim.x + threadIdx.x;
    if (e >= N_EDGES) return;
    int s = src[e];
    if (e == 0) {
        for (int i = 0; i <= s; ++i) row_ptr[i] = 0;
    } else {
        int sp = src[e - 1];
        for (int i = sp + 1; i <= s; ++i) row_ptr[i] = e;
    }
    if (e == N_EDGES - 1) {
        for (int i = s + 1; i <= N_NODES; ++i) row_ptr[i] = N_EDGES;
    }
}

// ---------------------------------------------------------------------------
// Kernel 3: out[i] = aw * sum_{e in seg(i)} dot(XP[i], XP[dst[e]]) * XP[dst[e]]
// One wave per node. 4 groups of 16 lanes; each group handles one edge per
// iteration: 16 lanes x float4 = the full 64-dim row (256B coalesced gather).
// Dot via 4 shfl_xor steps inside the group; cross-group combine at the end.
// ---------------------------------------------------------------------------
__global__ __launch_bounds__(256) void agnn_edge(const float* __restrict__ XP,
                                                 const int* __restrict__ row_ptr,
                                                 const int* __restrict__ dst,
                                                 const float* __restrict__ aw,
                                                 float* __restrict__ out) {
    const int t    = threadIdx.x;
    const int lane = t & 63;
    const int node = blockIdx.x * 4 + (t >> 6);
    if (node >= N_NODES) return;

    const int g  = lane >> 4;   // edge-group 0..3
    const int sl = lane & 15;   // dim-slot within group (4 floats each)

    const int lo = row_ptr[node];
    const int hi = row_ptr[node + 1];

    const float4 xq = *(const float4*)&XP[(size_t)node * OUT_DIM + sl * 4];
    float4 acc = make_float4(0.f, 0.f, 0.f, 0.f);

    for (int e0 = lo; e0 < hi; e0 += 4) {
        int e = e0 + g;
        float4 xd = make_float4(0.f, 0.f, 0.f, 0.f);
        if (e < hi) {
            int d = dst[e];
            xd = *(const float4*)&XP[(size_t)d * OUT_DIM + sl * 4];
        }
        float p = xq.x * xd.x + xq.y * xd.y + xq.z * xd.z + xq.w * xd.w;
        p += __shfl_xor(p, 1);
        p += __shfl_xor(p, 2);
        p += __shfl_xor(p, 4);
        p += __shfl_xor(p, 8);
        // p = dot(XP[node], XP[d]) for this group's edge (0 for inactive tail)
        acc.x += p * xd.x;
        acc.y += p * xd.y;
        acc.z += p * xd.z;
        acc.w += p * xd.w;
    }
    // Combine the 4 groups' partial sums (same dims live at same sl)
    #pragma unroll
    for (int m = 16; m < 64; m <<= 1) {
        acc.x += __shfl_xor(acc.x, m);
        acc.y += __shfl_xor(acc.y, m);
        acc.z += __shfl_xor(acc.z, m);
        acc.w += __shfl_xor(acc.w, m);
    }
    if (g == 0) {
        const float a = aw[0];
        float4 r = make_float4(acc.x * a, acc.y * a, acc.z * a, acc.w * a);
        *(float4*)&out[(size_t)node * OUT_DIM + sl * 4] = r;
    }
}

// ---------------------------------------------------------------------------
extern "C" void kernel_launch(void* const* d_in, const int* in_sizes, int n_in,
                              void* d_out, int out_size, void* d_ws, size_t ws_size,
                              hipStream_t stream) {
    const float* X   = (const float*)d_in[0];
    const float* W   = (const float*)d_in[1];
    const float* aw  = (const float*)d_in[2];
    const int*   src = (const int*)d_in[3];
    const int*   dst = (const int*)d_in[4];
    float* out = (float*)d_out;

    // Workspace layout: X_prime [N_NODES*OUT_DIM f32] | row_ptr [(N_NODES+1) i32]
    float* XP      = (float*)d_ws;
    int*   row_ptr = (int*)((char*)d_ws + (size_t)N_NODES * OUT_DIM * sizeof(float));

    gemm_xw<<<1536, 256, 0, stream>>>(X, W, XP, N_NODES);
    build_row_ptr<<<(N_EDGES + 255) / 256, 256, 0, stream>>>(src, row_ptr);
    agnn_edge<<<(N_NODES + 3) / 4, 256, 0, stream>>>(XP, row_ptr, dst, aw, out);
}

// Round 2
// 121.607 us; speedup vs baseline: 1.7243x; 1.7243x over previous
//
#include <hip/hip_runtime.h>

#define N_NODES 100000
#define N_EDGES 1600000
#define IN_DIM 128
#define OUT_DIM 64

// ---------------------------------------------------------------------------
// Kernel 1: X_prime = X @ W   (f32 vector ALU; no fp32 MFMA on CDNA4)
// Block = 256 threads = 4 waves. Tile = 64 rows.
//   lane  = row within tile (64 rows)
//   wave  = 16-column slice (4 waves cover the 64 output cols)
// Per k-quad: ONE swizzled ds_read_b128 of X (conflict-free) + 64 FMAs whose
// W operand is wave-uniform -> scalar loads (s_load_dwordx16) through the
// scalar cache: no LDS, no VALU cost for W. VALU-bound by design.
// ---------------------------------------------------------------------------
__global__ __launch_bounds__(256) void gemm_xw(const float* __restrict__ X,
                                               const float* __restrict__ W,
                                               float* __restrict__ XP,
                                               int nRows) {
    __shared__ float4 Xt[64 * 32];          // 32 KB, XOR-swizzled quads

    const int t    = threadIdx.x;
    const int lane = t & 63;
    // Force wave-uniformity so W indices scalarize to s_load.
    const int wid_u = __builtin_amdgcn_readfirstlane(t >> 6);
    const int c0    = wid_u * 16;

    const int nTiles = (nRows + 63) >> 6;
    for (int tile = blockIdx.x; tile < nTiles; tile += gridDim.x) {
        const int rowBase = tile << 6;

        // Stage 64 rows x 128 floats (2048 float4), coalesced, swizzled:
        // physical quad = q ^ (r&7)  (conflict-free b128 reads later).
        #pragma unroll
        for (int i = 0; i < 8; ++i) {
            int f = t + i * 256;
            int r = f >> 5;
            int q = f & 31;
            int gr = rowBase + r;
            float4 v = make_float4(0.f, 0.f, 0.f, 0.f);
            if (gr < nRows) v = *(const float4*)&X[(size_t)gr * IN_DIM + q * 4];
            Xt[r * 32 + (q ^ (r & 7))] = v;
        }
        __syncthreads();

        float acc[16];
        #pragma unroll
        for (int c = 0; c < 16; ++c) acc[c] = 0.f;

        #pragma unroll 2
        for (int kq = 0; kq < 32; ++kq) {
            float4 xv = Xt[lane * 32 + (kq ^ (lane & 7))];   // 1 b128, swizzled
            const float* Wk = &W[(size_t)kq * 4 * OUT_DIM + c0];  // uniform
            #pragma unroll
            for (int c = 0; c < 16; ++c) {
                acc[c] = fmaf(xv.x, Wk[c],               acc[c]);
                acc[c] = fmaf(xv.y, Wk[OUT_DIM + c],     acc[c]);
                acc[c] = fmaf(xv.z, Wk[2 * OUT_DIM + c], acc[c]);
                acc[c] = fmaf(xv.w, Wk[3 * OUT_DIM + c], acc[c]);
            }
        }

        // Epilogue: lane = row, 4x float4 (64B contiguous per lane).
        int gr = rowBase + lane;
        if (gr < nRows) {
            float* dst = &XP[(size_t)gr * OUT_DIM + c0];
            *(float4*)&dst[0]  = make_float4(acc[0],  acc[1],  acc[2],  acc[3]);
            *(float4*)&dst[4]  = make_float4(acc[4],  acc[5],  acc[6],  acc[7]);
            *(float4*)&dst[8]  = make_float4(acc[8],  acc[9],  acc[10], acc[11]);
            *(float4*)&dst[12] = make_float4(acc[12], acc[13], acc[14], acc[15]);
        }
        __syncthreads();
    }
}

// ---------------------------------------------------------------------------
// Kernel 2: row_ptr[i] = lower_bound(edge_src, i); edge_src sorted -> mark
// boundaries, total fill work O(N + E).
// ---------------------------------------------------------------------------
__global__ __launch_bounds__(256) void build_row_ptr(const int* __restrict__ src,
                                                     int* __restrict__ row_ptr) {
    int e = blockIdx.x * blockDim.x + threadIdx.x;
    if (e >= N_EDGES) return;
    int s = src[e];
    if (e == 0) {
        for (int i = 0; i <= s; ++i) row_ptr[i] = 0;
    } else {
        int sp = src[e - 1];
        for (int i = sp + 1; i <= s; ++i) row_ptr[i] = e;
    }
    if (e == N_EDGES - 1) {
        for (int i = s + 1; i <= N_NODES; ++i) row_ptr[i] = N_EDGES;
    }
}

// ---------------------------------------------------------------------------
// Kernel 3: out[i] = aw * sum_{e in seg(i)} dot(XP[i], XP[dst[e]]) * XP[dst[e]]
// One wave per node; 4 groups of 16 lanes = 4 edges in flight; 16 lanes x
// float4 = full 64-dim row (256B coalesced gather). Dot via 4 shfl_xor inside
// the group; cross-group combine at the end.
// ---------------------------------------------------------------------------
__global__ __launch_bounds__(256) void agnn_edge(const float* __restrict__ XP,
                                                 const int* __restrict__ row_ptr,
                                                 const int* __restrict__ dst,
                                                 const float* __restrict__ aw,
                                                 float* __restrict__ out) {
    const int t    = threadIdx.x;
    const int lane = t & 63;
    const int node = blockIdx.x * 4 + (t >> 6);
    if (node >= N_NODES) return;

    const int g  = lane >> 4;   // edge-group 0..3
    const int sl = lane & 15;   // dim-slot within group (4 floats each)

    const int lo = row_ptr[node];
    const int hi = row_ptr[node + 1];

    const float4 xq = *(const float4*)&XP[(size_t)node * OUT_DIM + sl * 4];
    float4 acc = make_float4(0.f, 0.f, 0.f, 0.f);

    for (int e0 = lo; e0 < hi; e0 += 4) {
        int e = e0 + g;
        float4 xd = make_float4(0.f, 0.f, 0.f, 0.f);
        if (e < hi) {
            int d = dst[e];
            xd = *(const float4*)&XP[(size_t)d * OUT_DIM + sl * 4];
        }
        float p = xq.x * xd.x + xq.y * xd.y + xq.z * xd.z + xq.w * xd.w;
        p += __shfl_xor(p, 1);
        p += __shfl_xor(p, 2);
        p += __shfl_xor(p, 4);
        p += __shfl_xor(p, 8);
        acc.x += p * xd.x;
        acc.y += p * xd.y;
        acc.z += p * xd.z;
        acc.w += p * xd.w;
    }
    #pragma unroll
    for (int m = 16; m < 64; m <<= 1) {
        acc.x += __shfl_xor(acc.x, m);
        acc.y += __shfl_xor(acc.y, m);
        acc.z += __shfl_xor(acc.z, m);
        acc.w += __shfl_xor(acc.w, m);
    }
    if (g == 0) {
        const float a = aw[0];
        float4 r = make_float4(acc.x * a, acc.y * a, acc.z * a, acc.w * a);
        *(float4*)&out[(size_t)node * OUT_DIM + sl * 4] = r;
    }
}

// ---------------------------------------------------------------------------
extern "C" void kernel_launch(void* const* d_in, const int* in_sizes, int n_in,
                              void* d_out, int out_size, void* d_ws, size_t ws_size,
                              hipStream_t stream) {
    const float* X   = (const float*)d_in[0];
    const float* W   = (const float*)d_in[1];
    const float* aw  = (const float*)d_in[2];
    const int*   src = (const int*)d_in[3];
    const int*   dst = (const int*)d_in[4];
    float* out = (float*)d_out;

    float* XP      = (float*)d_ws;
    int*   row_ptr = (int*)((char*)d_ws + (size_t)N_NODES * OUT_DIM * sizeof(float));

    const int nTiles = (N_NODES + 63) / 64;   // 1563
    gemm_xw<<<nTiles, 256, 0, stream>>>(X, W, XP, N_NODES);
    build_row_ptr<<<(N_EDGES + 255) / 256, 256, 0, stream>>>(src, row_ptr);
    agnn_edge<<<(N_NODES + 3) / 4, 256, 0, stream>>>(XP, row_ptr, dst, aw, out);
}

// Round 3
// 70.534 us; speedup vs baseline: 2.9729x; 1.7241x over previous
//
#include <hip/hip_runtime.h>
#include <stdint.h>

#define N_NODES 100000
#define N_EDGES 1600000
#define IN_DIM 128
#define OUT_DIM 64

typedef __bf16 bf16x8 __attribute__((ext_vector_type(8)));
typedef float  f32x4  __attribute__((ext_vector_type(4)));

__device__ __forceinline__ uint16_t f2bf(float f) {   // RNE
    uint32_t u = __float_as_uint(f);
    return (uint16_t)((u + 0x7fffu + ((u >> 16) & 1u)) >> 16);
}
__device__ __forceinline__ void unpack8(const uint4& v, float* x) {
    x[0] = __uint_as_float(v.x << 16); x[1] = __uint_as_float(v.x & 0xffff0000u);
    x[2] = __uint_as_float(v.y << 16); x[3] = __uint_as_float(v.y & 0xffff0000u);
    x[4] = __uint_as_float(v.z << 16); x[5] = __uint_as_float(v.z & 0xffff0000u);
    x[6] = __uint_as_float(v.w << 16); x[7] = __uint_as_float(v.w & 0xffff0000u);
}

// ---------------------------------------------------------------------------
// prep: blocks [0,6250) build row_ptr from sorted edge_src (O(N+E));
//       blocks [6250,6254) pack W into per-lane MFMA B-fragments:
//       frag f = ct*4+ks; lane l holds B[k = ks*32+(l>>4)*8 + j][col = ct*16+(l&15)]
//       packed as bf16 pairs (low half = even element).
// ---------------------------------------------------------------------------
__global__ __launch_bounds__(256) void prep(const int* __restrict__ src,
                                            const float* __restrict__ W,
                                            int* __restrict__ row_ptr,
                                            uint4* __restrict__ Wfrag) {
    const int b = blockIdx.x;
    if (b < N_EDGES / 256) {
        int e = b * 256 + threadIdx.x;
        int s = src[e];
        if (e == 0) {
            for (int i = 0; i <= s; ++i) row_ptr[i] = 0;
        } else {
            int sp = src[e - 1];
            for (int i = sp + 1; i <= s; ++i) row_ptr[i] = e;
        }
        if (e == N_EDGES - 1) {
            for (int i = s + 1; i <= N_NODES; ++i) row_ptr[i] = N_EDGES;
        }
    } else {
        int item = (b - N_EDGES / 256) * 256 + threadIdx.x;   // 0..1023
        if (item < 1024) {
            int f = item >> 6, lane = item & 63;
            int ct = f >> 2, ks = f & 3;
            int col = ct * 16 + (lane & 15);
            int kb  = ks * 32 + (lane >> 4) * 8;
            uint32_t u[4];
            #pragma unroll
            for (int j = 0; j < 4; ++j) {
                uint32_t lo = f2bf(W[(kb + 2 * j)     * OUT_DIM + col]);
                uint32_t hi = f2bf(W[(kb + 2 * j + 1) * OUT_DIM + col]);
                u[j] = lo | (hi << 16);
            }
            Wfrag[f * 64 + lane] = make_uint4(u[0], u[1], u[2], u[3]);
        }
    }
}

// ---------------------------------------------------------------------------
// GEMM: XPb = bf16(X @ W) via mfma_f32_16x16x32_bf16. No LDS: A-frags are
// coalesced direct global reads (each X row-slice read exactly once by its
// owning wave); B-frags (whole W) live in 64 VGPRs, loaded coalesced from
// Wfrag. Wave = 16 rows x 64 cols; block = 4 waves = 64 rows.
// ---------------------------------------------------------------------------
__global__ __launch_bounds__(256) void gemm_xw(const float* __restrict__ X,
                                               const uint4* __restrict__ Wfrag,
                                               uint16_t* __restrict__ XPb,
                                               int nRows) {
    const int t = threadIdx.x;
    const int lane = t & 63;

    bf16x8 bfr[16];
    #pragma unroll
    for (int f = 0; f < 16; ++f)
        bfr[f] = __builtin_bit_cast(bf16x8, Wfrag[f * 64 + lane]);

    const int rowBase = blockIdx.x * 64 + (t >> 6) * 16;
    const int r  = rowBase + (lane & 15);
    const int kb = (lane >> 4) * 8;
    const bool inb = r < nRows;

    f32x4 acc[4] = {{0,0,0,0},{0,0,0,0},{0,0,0,0},{0,0,0,0}};

    #pragma unroll
    for (int ks = 0; ks < 4; ++ks) {
        float4 x0 = make_float4(0.f,0.f,0.f,0.f), x1 = x0;
        if (inb) {
            const float* p = &X[(size_t)r * IN_DIM + ks * 32 + kb];
            x0 = *(const float4*)&p[0];
            x1 = *(const float4*)&p[4];
        }
        bf16x8 a;
        a[0]=(__bf16)x0.x; a[1]=(__bf16)x0.y; a[2]=(__bf16)x0.z; a[3]=(__bf16)x0.w;
        a[4]=(__bf16)x1.x; a[5]=(__bf16)x1.y; a[6]=(__bf16)x1.z; a[7]=(__bf16)x1.w;
        #pragma unroll
        for (int ct = 0; ct < 4; ++ct)
            acc[ct] = __builtin_amdgcn_mfma_f32_16x16x32_bf16(a, bfr[ct * 4 + ks], acc[ct], 0, 0, 0);
    }

    // C/D layout: col = lane&15, row = (lane>>4)*4 + reg   [m89-verified]
    const int orow = rowBase + (lane >> 4) * 4;
    const int ocol = lane & 15;
    #pragma unroll
    for (int ct = 0; ct < 4; ++ct) {
        #pragma unroll
        for (int rr = 0; rr < 4; ++rr) {
            int gr = orow + rr;
            if (gr < nRows) XPb[(size_t)gr * OUT_DIM + ct * 16 + ocol] = f2bf(acc[ct][rr]);
        }
    }
}

// ---------------------------------------------------------------------------
// Edge kernel: out[i] = aw * sum_e dot(XP[i], XP[dst_e]) * XP[dst_e]
// Wave per node; 8 groups x 8 lanes; lane holds 8 bf16 dims (16B load = full
// 128B row per group). 16 edges per wave-iteration (2 per group) -> 2 gathers
// in flight. Dot reduce: 3 shfl_xor in-group; cross-group combine at end.
// ---------------------------------------------------------------------------
__global__ __launch_bounds__(256) void agnn_edge(const uint16_t* __restrict__ XPb,
                                                 const int* __restrict__ row_ptr,
                                                 const int* __restrict__ dst,
                                                 const float* __restrict__ aw,
                                                 float* __restrict__ out) {
    const int t = threadIdx.x;
    const int lane = t & 63;
    const int node = blockIdx.x * 4 + (t >> 6);
    if (node >= N_NODES) return;
    const int g = lane >> 3, sl = lane & 7;

    const int lo = row_ptr[node];
    const int hi = row_ptr[node + 1];

    float xq[8];
    {
        uint4 q = *(const uint4*)&XPb[(size_t)node * OUT_DIM + sl * 8];
        unpack8(q, xq);
    }
    float acc[8] = {0.f,0.f,0.f,0.f,0.f,0.f,0.f,0.f};

    for (int e0 = lo; e0 < hi; e0 += 16) {
        const int eA = e0 + g, eB = eA + 8;
        uint4 ra = make_uint4(0u,0u,0u,0u), rb = ra;
        if (eA < hi) {
            int d = dst[eA];
            ra = *(const uint4*)&XPb[(size_t)d * OUT_DIM + sl * 8];
        }
        if (eB < hi) {
            int d = dst[eB];
            rb = *(const uint4*)&XPb[(size_t)d * OUT_DIM + sl * 8];
        }
        float xd[8];
        unpack8(ra, xd);
        float p = xq[0] * xd[0];
        #pragma unroll
        for (int j = 1; j < 8; ++j) p = fmaf(xq[j], xd[j], p);
        p += __shfl_xor(p, 1); p += __shfl_xor(p, 2); p += __shfl_xor(p, 4);
        #pragma unroll
        for (int j = 0; j < 8; ++j) acc[j] = fmaf(p, xd[j], acc[j]);

        unpack8(rb, xd);
        float p2 = xq[0] * xd[0];
        #pragma unroll
        for (int j = 1; j < 8; ++j) p2 = fmaf(xq[j], xd[j], p2);
        p2 += __shfl_xor(p2, 1); p2 += __shfl_xor(p2, 2); p2 += __shfl_xor(p2, 4);
        #pragma unroll
        for (int j = 0; j < 8; ++j) acc[j] = fmaf(p2, xd[j], acc[j]);
    }

    #pragma unroll
    for (int m = 8; m <= 32; m <<= 1) {
        #pragma unroll
        for (int j = 0; j < 8; ++j) acc[j] += __shfl_xor(acc[j], m);
    }
    if (g == 0) {
        const float a = aw[0];
        float* o = &out[(size_t)node * OUT_DIM + sl * 8];
        *(float4*)&o[0] = make_float4(acc[0]*a, acc[1]*a, acc[2]*a, acc[3]*a);
        *(float4*)&o[4] = make_float4(acc[4]*a, acc[5]*a, acc[6]*a, acc[7]*a);
    }
}

// ---------------------------------------------------------------------------
extern "C" void kernel_launch(void* const* d_in, const int* in_sizes, int n_in,
                              void* d_out, int out_size, void* d_ws, size_t ws_size,
                              hipStream_t stream) {
    const float* X   = (const float*)d_in[0];
    const float* W   = (const float*)d_in[1];
    const float* aw  = (const float*)d_in[2];
    const int*   src = (const int*)d_in[3];
    const int*   dst = (const int*)d_in[4];
    float* out = (float*)d_out;

    // ws layout: XPb bf16 [N*64] | row_ptr int [N+1] | Wfrag uint4 [16*64]
    uint16_t* XPb     = (uint16_t*)d_ws;
    int*      row_ptr = (int*)((char*)d_ws + (size_t)N_NODES * OUT_DIM * 2);
    uint4*    Wfrag   = (uint4*)((char*)d_ws + 13200016);   // 16B-aligned past row_ptr

    prep<<<N_EDGES / 256 + 4, 256, 0, stream>>>(src, W, row_ptr, Wfrag);
    gemm_xw<<<(N_NODES + 63) / 64, 256, 0, stream>>>(X, Wfrag, XPb, N_NODES);
    agnn_edge<<<N_NODES / 4, 256, 0, stream>>>(XPb, row_ptr, dst, aw, out);
}

// Round 4
// 67.217 us; speedup vs baseline: 3.1196x; 1.0493x over previous
//
#include <hip/hip_runtime.h>
#include <stdint.h>

#define N_NODES 100000
#define N_EDGES 1600000
#define IN_DIM 128
#define OUT_DIM 64

typedef __bf16    bf16x8 __attribute__((ext_vector_type(8)));
typedef float     f32x4  __attribute__((ext_vector_type(4)));
typedef _Float16  h2     __attribute__((ext_vector_type(2)));

__device__ __forceinline__ uint16_t f2bf(float f) {   // RNE
    uint32_t u = __float_as_uint(f);
    return (uint16_t)((u + 0x7fffu + ((u >> 16) & 1u)) >> 16);
}
__device__ __forceinline__ float hdot8(uint4 a, uint4 b, float c) {
#if __has_builtin(__builtin_amdgcn_fdot2)
    c = __builtin_amdgcn_fdot2(__builtin_bit_cast(h2, a.x), __builtin_bit_cast(h2, b.x), c, false);
    c = __builtin_amdgcn_fdot2(__builtin_bit_cast(h2, a.y), __builtin_bit_cast(h2, b.y), c, false);
    c = __builtin_amdgcn_fdot2(__builtin_bit_cast(h2, a.z), __builtin_bit_cast(h2, b.z), c, false);
    c = __builtin_amdgcn_fdot2(__builtin_bit_cast(h2, a.w), __builtin_bit_cast(h2, b.w), c, false);
#else
    const h2 qa[4] = {__builtin_bit_cast(h2,a.x),__builtin_bit_cast(h2,a.y),
                      __builtin_bit_cast(h2,a.z),__builtin_bit_cast(h2,a.w)};
    const h2 qb[4] = {__builtin_bit_cast(h2,b.x),__builtin_bit_cast(h2,b.y),
                      __builtin_bit_cast(h2,b.z),__builtin_bit_cast(h2,b.w)};
    #pragma unroll
    for (int i = 0; i < 4; ++i) {
        c = fmaf((float)qa[i][0], (float)qb[i][0], c);
        c = fmaf((float)qa[i][1], (float)qb[i][1], c);
    }
#endif
    return c;
}

// ---------------------------------------------------------------------------
// prep: blocks [0,6250) build row_ptr from sorted edge_src (O(N+E));
//       blocks [6250,6254) pack W into per-lane MFMA B-fragments (bf16 pairs):
//       frag f = ct*4+ks; lane l holds B[k = ks*32+(l>>4)*8+j][col = ct*16+(l&15)]
// ---------------------------------------------------------------------------
__global__ __launch_bounds__(256) void prep(const int* __restrict__ src,
                                            const float* __restrict__ W,
                                            int* __restrict__ row_ptr,
                                            uint4* __restrict__ Wfrag) {
    const int b = blockIdx.x;
    if (b < N_EDGES / 256) {
        int e = b * 256 + threadIdx.x;
        int s = src[e];
        if (e == 0) {
            for (int i = 0; i <= s; ++i) row_ptr[i] = 0;
        } else {
            int sp = src[e - 1];
            for (int i = sp + 1; i <= s; ++i) row_ptr[i] = e;
        }
        if (e == N_EDGES - 1) {
            for (int i = s + 1; i <= N_NODES; ++i) row_ptr[i] = N_EDGES;
        }
    } else {
        int item = (b - N_EDGES / 256) * 256 + threadIdx.x;   // 0..1023
        if (item < 1024) {
            int f = item >> 6, lane = item & 63;
            int ct = f >> 2, ks = f & 3;
            int col = ct * 16 + (lane & 15);
            int kb  = ks * 32 + (lane >> 4) * 8;
            uint32_t u[4];
            #pragma unroll
            for (int j = 0; j < 4; ++j) {
                uint32_t lo = f2bf(W[(kb + 2 * j)     * OUT_DIM + col]);
                uint32_t hi = f2bf(W[(kb + 2 * j + 1) * OUT_DIM + col]);
                u[j] = lo | (hi << 16);
            }
            Wfrag[f * 64 + lane] = make_uint4(u[0], u[1], u[2], u[3]);
        }
    }
}

// ---------------------------------------------------------------------------
// GEMM: XPh = f16(X @ W) via mfma_f32_16x16x32_bf16. No LDS; A-frags direct
// coalesced global reads (X read exactly once); whole W lives in 64 VGPRs.
// Wave = 16 rows x 64 cols; block = 4 waves.
// ---------------------------------------------------------------------------
__global__ __launch_bounds__(256) void gemm_xw(const float* __restrict__ X,
                                               const uint4* __restrict__ Wfrag,
                                               _Float16* __restrict__ XPh,
                                               int nRows) {
    const int t = threadIdx.x;
    const int lane = t & 63;

    bf16x8 bfr[16];
    #pragma unroll
    for (int f = 0; f < 16; ++f)
        bfr[f] = __builtin_bit_cast(bf16x8, Wfrag[f * 64 + lane]);

    const int rowBase = blockIdx.x * 64 + (t >> 6) * 16;
    const int r  = rowBase + (lane & 15);
    const int kb = (lane >> 4) * 8;
    const bool inb = r < nRows;

    f32x4 acc[4] = {{0,0,0,0},{0,0,0,0},{0,0,0,0},{0,0,0,0}};

    #pragma unroll
    for (int ks = 0; ks < 4; ++ks) {
        float4 x0 = make_float4(0.f,0.f,0.f,0.f), x1 = x0;
        if (inb) {
            const float* p = &X[(size_t)r * IN_DIM + ks * 32 + kb];
            x0 = *(const float4*)&p[0];
            x1 = *(const float4*)&p[4];
        }
        bf16x8 a;
        a[0]=(__bf16)x0.x; a[1]=(__bf16)x0.y; a[2]=(__bf16)x0.z; a[3]=(__bf16)x0.w;
        a[4]=(__bf16)x1.x; a[5]=(__bf16)x1.y; a[6]=(__bf16)x1.z; a[7]=(__bf16)x1.w;
        #pragma unroll
        for (int ct = 0; ct < 4; ++ct)
            acc[ct] = __builtin_amdgcn_mfma_f32_16x16x32_bf16(a, bfr[ct * 4 + ks], acc[ct], 0, 0, 0);
    }

    // C/D layout: col = lane&15, row = (lane>>4)*4 + reg   [m89-verified]
    const int orow = rowBase + (lane >> 4) * 4;
    const int ocol = lane & 15;
    #pragma unroll
    for (int ct = 0; ct < 4; ++ct) {
        #pragma unroll
        for (int rr = 0; rr < 4; ++rr) {
            int gr = orow + rr;
            if (gr < nRows) XPh[(size_t)gr * OUT_DIM + ct * 16 + ocol] = (_Float16)acc[ct][rr];
        }
    }
}

// ---------------------------------------------------------------------------
// Edge kernel: out[i] = aw * sum_e dot(XP[i], XP[dst_e]) * XP[dst_e]
// Wave per node; 8 groups x 8 lanes; lane holds 8 f16 dims (16B = full 128B
// row per group). Batch phase: load dst[] for 4 chunks (32 edges), then issue
// all 4 row-gathers back-to-back (64 cache lines in flight, ONE latency
// exposure for deg<=32). Dot: 4x v_dot2_f32_f16 + 3 shfl. Accum: v_fma_mix.
// ---------------------------------------------------------------------------
__global__ __launch_bounds__(256, 6) void agnn_edge(const _Float16* __restrict__ XPh,
                                                    const int* __restrict__ row_ptr,
                                                    const int* __restrict__ dst,
                                                    const float* __restrict__ aw,
                                                    float* __restrict__ out) {
    const int t = threadIdx.x;
    const int lane = t & 63;
    const int node = blockIdx.x * 4 + (t >> 6);
    const int g = lane >> 3, sl = lane & 7;

    const int lo = row_ptr[node];
    const int hi = row_ptr[node + 1];

    const uint4 q = *(const uint4*)&XPh[(size_t)node * OUT_DIM + sl * 8];
    float acc[8] = {0.f,0.f,0.f,0.f,0.f,0.f,0.f,0.f};

    for (int base = lo; base < hi; base += 32) {
        // 1) gather indices for this wave's 4 chunks (independent loads)
        int dx[4];
        #pragma unroll
        for (int c = 0; c < 4; ++c) {
            int e = base + c * 8 + g;
            dx[c] = (e < hi) ? dst[e] : -1;
        }
        // 2) issue all row gathers back-to-back
        uint4 xd[4];
        #pragma unroll
        for (int c = 0; c < 4; ++c) {
            xd[c] = make_uint4(0u, 0u, 0u, 0u);
            if (dx[c] >= 0)
                xd[c] = *(const uint4*)&XPh[(size_t)dx[c] * OUT_DIM + sl * 8];
        }
        // 3) compute
        #pragma unroll
        for (int c = 0; c < 4; ++c) {
            float p = hdot8(q, xd[c], 0.f);
            p += __shfl_xor(p, 1);
            p += __shfl_xor(p, 2);
            p += __shfl_xor(p, 4);
            const h2 d0 = __builtin_bit_cast(h2, xd[c].x);
            const h2 d1 = __builtin_bit_cast(h2, xd[c].y);
            const h2 d2 = __builtin_bit_cast(h2, xd[c].z);
            const h2 d3 = __builtin_bit_cast(h2, xd[c].w);
            acc[0] = fmaf(p, (float)d0[0], acc[0]);
            acc[1] = fmaf(p, (float)d0[1], acc[1]);
            acc[2] = fmaf(p, (float)d1[0], acc[2]);
            acc[3] = fmaf(p, (float)d1[1], acc[3]);
            acc[4] = fmaf(p, (float)d2[0], acc[4]);
            acc[5] = fmaf(p, (float)d2[1], acc[5]);
            acc[6] = fmaf(p, (float)d3[0], acc[6]);
            acc[7] = fmaf(p, (float)d3[1], acc[7]);
        }
    }

    // cross-group combine (same dims live at same sl)
    #pragma unroll
    for (int m = 8; m <= 32; m <<= 1) {
        #pragma unroll
        for (int j = 0; j < 8; ++j) acc[j] += __shfl_xor(acc[j], m);
    }
    if (g == 0) {
        const float a = aw[0];
        float* o = &out[(size_t)node * OUT_DIM + sl * 8];
        *(float4*)&o[0] = make_float4(acc[0]*a, acc[1]*a, acc[2]*a, acc[3]*a);
        *(float4*)&o[4] = make_float4(acc[4]*a, acc[5]*a, acc[6]*a, acc[7]*a);
    }
}

// ---------------------------------------------------------------------------
extern "C" void kernel_launch(void* const* d_in, const int* in_sizes, int n_in,
                              void* d_out, int out_size, void* d_ws, size_t ws_size,
                              hipStream_t stream) {
    const float* X   = (const float*)d_in[0];
    const float* W   = (const float*)d_in[1];
    const float* aw  = (const float*)d_in[2];
    const int*   src = (const int*)d_in[3];
    const int*   dst = (const int*)d_in[4];
    float* out = (float*)d_out;

    // ws layout: XPh f16 [N*64] | row_ptr int [N+1] | Wfrag uint4 [16*64]
    _Float16* XPh     = (_Float16*)d_ws;
    int*      row_ptr = (int*)((char*)d_ws + (size_t)N_NODES * OUT_DIM * 2);
    uint4*    Wfrag   = (uint4*)((char*)d_ws + 13200016);   // 16B-aligned

    prep<<<N_EDGES / 256 + 4, 256, 0, stream>>>(src, W, row_ptr, Wfrag);
    gemm_xw<<<(N_NODES + 63) / 64, 256, 0, stream>>>(X, Wfrag, XPh, N_NODES);
    agnn_edge<<<N_NODES / 4, 256, 0, stream>>>(XPh, row_ptr, dst, aw, out);
}